// Round 2
// baseline (173.249 us; speedup 1.0000x reference)
//
#include <hip/hip_runtime.h>

// LocalAttention: bf16 MFMA GEMMs (m97 pattern) + LDS-free MFMA flash attention
// (swapped QK^T, lane-local online softmax, V^T global layout).
// ws layout (bytes): xb[0,8M) w1b[8M,14M) wob[14M,16M) Q[16M,24M) K[24M,32M)
//                    VT[32M,40M) attn[40M,48M)   -- all bf16 (short)

#define S_LEN 2048
#define NH 16
#define DH 64
#define DM 1024
#define WIN 128

typedef __attribute__((ext_vector_type(8))) short short8;
typedef __attribute__((ext_vector_type(4))) short short4_t;
typedef __attribute__((ext_vector_type(4))) float f32x4;
typedef __attribute__((ext_vector_type(16))) float f32x16;

__device__ __forceinline__ unsigned short f2bf(float f){
  unsigned u = __float_as_uint(f);
  u += 0x7fffu + ((u >> 16) & 1u);   // RTNE
  return (unsigned short)(u >> 16);
}
__device__ __forceinline__ unsigned pk2(float lo, float hi){
  return (unsigned)f2bf(lo) | ((unsigned)f2bf(hi) << 16);
}

__device__ __forceinline__ void async16(void* l, const void* g){
  __builtin_amdgcn_global_load_lds((const __attribute__((address_space(1))) void*)g,
                                   (__attribute__((address_space(3))) void*)l, 16, 0, 0);
}

__global__ void cvt_bf16(const float* __restrict__ in, short* __restrict__ out, int n){
  int i = (blockIdx.x * blockDim.x + threadIdx.x) * 4;
  if (i >= n) return;
  float4 v = *(const float4*)(in + i);
  short4_t o;
  o.x = (short)f2bf(v.x); o.y = (short)f2bf(v.y);
  o.z = (short)f2bf(v.z); o.w = (short)f2bf(v.w);
  *(short4_t*)(out + i) = o;
}

// ---------------- QKV GEMM: C[4096,3072] = X[4096,1024] * W^T, W row-major [3072,1024]
// Q,K written [b][h][s][64] (Q pre-scaled by 1/8); V written TRANSPOSED [b][h][64][s].
__global__ __launch_bounds__(256) void gemm_qkv(
    const short* __restrict__ A, const short* __restrict__ Bw,
    const float* __restrict__ bias,
    short* __restrict__ Qb, short* __restrict__ Kb, short* __restrict__ Vb)
{
  __shared__ short As[128*32], Bs[128*32];
  const int K = 1024;
  int tid = threadIdx.x;
  int lane = tid & 63, wv = tid >> 6;
  int wr = wv >> 1, wc = wv & 1;
  int lr = lane & 15, lh = lane >> 4;
  int m0 = blockIdx.y * 128, n0 = blockIdx.x * 128;

  f32x4 acc[4][4] = {};
  for (int kt = 0; kt < K; kt += 32) {
    #pragma unroll
    for (int i = 0; i < 2; ++i) {
      int c = i*256 + tid;
      int row = c >> 2, col = (c & 3) << 3;
      async16(&As[c*8], A  + (size_t)(m0+row)*K + kt + col);
      async16(&Bs[c*8], Bw + (size_t)(n0+row)*K + kt + col);
    }
    __syncthreads();
    short8 af[4], bfr[4];
    #pragma unroll
    for (int m = 0; m < 4; ++m) af[m]  = *(const short8*)&As[(wr*64 + m*16 + lr)*32 + lh*8];
    #pragma unroll
    for (int n = 0; n < 4; ++n) bfr[n] = *(const short8*)&Bs[(wc*64 + n*16 + lr)*32 + lh*8];
    #pragma unroll
    for (int m = 0; m < 4; ++m)
      #pragma unroll
      for (int n = 0; n < 4; ++n)
        acc[m][n] = __builtin_amdgcn_mfma_f32_16x16x32_bf16(af[m], bfr[n], acc[m][n], 0, 0, 0);
    __syncthreads();
  }
  #pragma unroll
  for (int m = 0; m < 4; ++m) {
    #pragma unroll
    for (int n = 0; n < 4; ++n) {
      int col = n0 + wc*64 + n*16 + lr;
      float bv = bias[col];
      int which = col >> 10, cc = col & 1023;
      int h = cc >> 6, d = cc & 63;
      float scl = which == 0 ? 0.125f : 1.0f;   // fold 1/sqrt(Dh) into Q
      #pragma unroll
      for (int r = 0; r < 4; ++r) {
        int grow = m0 + wr*64 + m*16 + lh*4 + r;   // C/D: col=lane&15, row=(lane>>4)*4+r
        int b = grow >> 11, s = grow & 2047;
        float v = (acc[m][n][r] + bv) * scl;
        if (which == 2) {
          Vb[((size_t)(b*NH + h)*DH + d)*S_LEN + s] = (short)f2bf(v);   // V^T
        } else {
          short* dst = which == 0 ? Qb : Kb;
          dst[(((size_t)b*NH + h)*S_LEN + s)*DH + d] = (short)f2bf(v);
        }
      }
    }
  }
}

// ---------------- Out GEMM: Out[4096,1024] = Attn[4096,1024] * Wo^T + bo (fp32 out)
__global__ __launch_bounds__(256) void gemm_out(
    const short* __restrict__ A, const short* __restrict__ Bw,
    const float* __restrict__ bias, float* __restrict__ Out)
{
  __shared__ short As[128*32], Bs[128*32];
  const int K = 1024;
  int tid = threadIdx.x;
  int lane = tid & 63, wv = tid >> 6;
  int wr = wv >> 1, wc = wv & 1;
  int lr = lane & 15, lh = lane >> 4;
  int m0 = blockIdx.y * 128, n0 = blockIdx.x * 128;

  f32x4 acc[4][4] = {};
  for (int kt = 0; kt < K; kt += 32) {
    #pragma unroll
    for (int i = 0; i < 2; ++i) {
      int c = i*256 + tid;
      int row = c >> 2, col = (c & 3) << 3;
      async16(&As[c*8], A  + (size_t)(m0+row)*K + kt + col);
      async16(&Bs[c*8], Bw + (size_t)(n0+row)*K + kt + col);
    }
    __syncthreads();
    short8 af[4], bfr[4];
    #pragma unroll
    for (int m = 0; m < 4; ++m) af[m]  = *(const short8*)&As[(wr*64 + m*16 + lr)*32 + lh*8];
    #pragma unroll
    for (int n = 0; n < 4; ++n) bfr[n] = *(const short8*)&Bs[(wc*64 + n*16 + lr)*32 + lh*8];
    #pragma unroll
    for (int m = 0; m < 4; ++m)
      #pragma unroll
      for (int n = 0; n < 4; ++n)
        acc[m][n] = __builtin_amdgcn_mfma_f32_16x16x32_bf16(af[m], bfr[n], acc[m][n], 0, 0, 0);
    __syncthreads();
  }
  #pragma unroll
  for (int m = 0; m < 4; ++m) {
    #pragma unroll
    for (int n = 0; n < 4; ++n) {
      int col = n0 + wc*64 + n*16 + lr;
      float bv = bias[col];
      #pragma unroll
      for (int r = 0; r < 4; ++r) {
        int grow = m0 + wr*64 + m*16 + lh*4 + r;
        Out[(size_t)grow*DM + col] = acc[m][n][r] + bv;
      }
    }
  }
}

// ---------------- MFMA flash attention, LDS-free, swapped operands.
// Block 256 = 4 waves; each wave owns 32 queries (q0w..q0w+31) of one (b,h).
// Per 32-key tile: S^T = sum_kc mfma(A=K_rows, B=Q_rows)  [32x32x16 bf16]
//   -> lane holds col q=(lane&31), rows key=(r&3)+8*(r>>2)+4*(lane>>5)
//   -> online softmax per-lane scalar (m,l); half-exchange via shfl_xor 32.
// P->bf16 B-frags via scalar RTNE packs + 4x shfl/select (permlane dataflow).
// O^T += mfma(A=V^T_rows, B=P^T). V^T read 16B-contiguous from global.
__global__ __launch_bounds__(256) void attn_mfma(
    const short* __restrict__ Qb, const short* __restrict__ Kb,
    const short* __restrict__ VTb, short* __restrict__ Ob)
{
  int tid = threadIdx.x;
  int lane = tid & 63, wv = tid >> 6;
  int q31 = lane & 31, h2 = lane >> 5;
  int bh = blockIdx.y;
  int q0w = blockIdx.x * 128 + wv * 32;
  int qa = q0w + q31;

  const short* Qg = Qb  + (size_t)bh * S_LEN * DH;
  const short* Kg = Kb  + (size_t)bh * S_LEN * DH;
  const short* Vg = VTb + (size_t)bh * DH * S_LEN;

  short8 qf[4];
  #pragma unroll
  for (int kc = 0; kc < 4; ++kc)
    qf[kc] = *(const short8*)(Qg + (size_t)qa * DH + kc*16 + h2*8);

  int ks = q0w - WIN; if (ks < 0) ks = 0;
  int ke = q0w + 32 + WIN; if (ke > S_LEN) ke = S_LEN;

  f32x16 o0 = {}, o1 = {};          // O^T tiles: d 0..31 / 32..63, col q
  float m = -1e37f, l = 0.f;

  for (int t0 = ks; t0 < ke; t0 += 32) {
    f32x16 s = {};
    #pragma unroll
    for (int kc = 0; kc < 4; ++kc) {
      short8 kf = *(const short8*)(Kg + (size_t)(t0 + q31) * DH + kc*16 + h2*8);
      s = __builtin_amdgcn_mfma_f32_32x32x16_bf16(kf, qf[kc], s, 0, 0, 0);
    }
    float p[16];
    float tm = -1e38f;
    #pragma unroll
    for (int r = 0; r < 16; ++r) {
      int key = t0 + (r & 3) + 8*(r >> 2) + 4*h2;
      bool ok = (key >= qa - WIN) && (key <= qa + WIN);
      p[r] = ok ? s[r] : -1e38f;
      tm = fmaxf(tm, p[r]);
    }
    tm = fmaxf(tm, __shfl_xor(tm, 32, 64));
    float mn = fmaxf(m, tm);
    float sc = __expf(m - mn);
    float ts = 0.f;
    #pragma unroll
    for (int r = 0; r < 16; ++r) { p[r] = __expf(p[r] - mn); ts += p[r]; }
    ts += __shfl_xor(ts, 32, 64);
    l = l * sc + ts;
    m = mn;
    #pragma unroll
    for (int r = 0; r < 16; ++r) { o0[r] *= sc; o1[r] *= sc; }

    #pragma unroll
    for (int kc2 = 0; kc2 < 2; ++kc2) {
      unsigned A1 = pk2(p[kc2*8+0], p[kc2*8+1]);
      unsigned A2 = pk2(p[kc2*8+2], p[kc2*8+3]);
      unsigned B1 = pk2(p[kc2*8+4], p[kc2*8+5]);
      unsigned B2 = pk2(p[kc2*8+6], p[kc2*8+7]);
      unsigned sA1 = (unsigned)__shfl_xor((int)A1, 32, 64);
      unsigned sA2 = (unsigned)__shfl_xor((int)A2, 32, 64);
      unsigned sB1 = (unsigned)__shfl_xor((int)B1, 32, 64);
      unsigned sB2 = (unsigned)__shfl_xor((int)B2, 32, 64);
      union { unsigned u[4]; short8 v; } pa;
      pa.u[0] = h2 ? sB1 : A1;          // keys 8*h2+{0,1}
      pa.u[1] = h2 ? sB2 : A2;          // keys 8*h2+{2,3}
      pa.u[2] = h2 ? B1 : sA1;          // keys 8*h2+{4,5}
      pa.u[3] = h2 ? B2 : sA2;          // keys 8*h2+{6,7}
      #pragma unroll
      for (int mt = 0; mt < 2; ++mt) {
        short8 vf = *(const short8*)(Vg + (size_t)(mt*32 + q31) * S_LEN + t0 + kc2*16 + h2*8);
        if (mt == 0) o0 = __builtin_amdgcn_mfma_f32_32x32x16_bf16(vf, pa.v, o0, 0, 0, 0);
        else         o1 = __builtin_amdgcn_mfma_f32_32x32x16_bf16(vf, pa.v, o1, 0, 0, 0);
      }
    }
  }

  float inv = 1.0f / l;
  int b = bh >> 4, hh = bh & 15;
  unsigned* Orow = (unsigned*)Ob + ((size_t)b*S_LEN + qa) * (DM/2) + hh*32;
  #pragma unroll
  for (int mt = 0; mt < 2; ++mt) {
    #pragma unroll
    for (int a = 0; a < 4; ++a) {
      #pragma unroll
      for (int e = 0; e < 2; ++e) {
        int r = 4*a + 2*e;
        float x0 = (mt ? o1[r]   : o0[r])   * inv;
        float x1 = (mt ? o1[r+1] : o0[r+1]) * inv;
        int d = 2*e + 8*a + 4*h2 + 32*mt;    // even; pair (d, d+1)
        Orow[d >> 1] = pk2(x0, x1);
      }
    }
  }
}

extern "C" void kernel_launch(void* const* d_in, const int* in_sizes, int n_in,
                              void* d_out, int out_size, void* d_ws, size_t ws_size,
                              hipStream_t stream) {
  const float* x  = (const float*)d_in[0];   // [2,2048,1024]
  const float* w1 = (const float*)d_in[1];   // [3072,1024]
  const float* b1 = (const float*)d_in[2];   // [3072]
  const float* wo = (const float*)d_in[3];   // [1024,1024]
  const float* bo = (const float*)d_in[4];   // [1024]
  float* out = (float*)d_out;

  char* ws = (char*)d_ws;
  short* xb  = (short*)(ws);
  short* w1b = (short*)(ws + (size_t)8*1024*1024);
  short* wob = (short*)(ws + (size_t)14*1024*1024);
  short* Qb  = (short*)(ws + (size_t)16*1024*1024);
  short* Kb  = (short*)(ws + (size_t)24*1024*1024);
  short* VTb = (short*)(ws + (size_t)32*1024*1024);
  short* Ab  = (short*)(ws + (size_t)40*1024*1024);

  cvt_bf16<<<dim3(4096), dim3(256), 0, stream>>>(x,  xb,  2*2048*1024);
  cvt_bf16<<<dim3(3072), dim3(256), 0, stream>>>(w1, w1b, 3072*1024);
  cvt_bf16<<<dim3(1024), dim3(256), 0, stream>>>(wo, wob, 1024*1024);
  gemm_qkv<<<dim3(24, 32), dim3(256), 0, stream>>>(xb, w1b, b1, Qb, Kb, VTb);
  attn_mfma<<<dim3(16, 32), dim3(256), 0, stream>>>(Qb, Kb, VTb, Ab);
  gemm_out<<<dim3(8, 32), dim3(256), 0, stream>>>(Ab, wob, bo, out);
}